// Round 1
// baseline (348.494 us; speedup 1.0000x reference)
//
#include <hip/hip_runtime.h>
#include <hip/hip_bf16.h>
#include <hip/hip_fp16.h>

using half8  = __attribute__((ext_vector_type(8))) _Float16;
using half4  = __attribute__((ext_vector_type(4))) _Float16;
using float4v = __attribute__((ext_vector_type(4))) float;

#define A_DIM 4
#define M_DIM 2048
#define E_DIM 1024
#define H_DIM 16
#define C_DIM 64
#define PLANE (M_DIM * C_DIM)            // 131072 elements per (a,h)
#define PROJ_ELEMS (A_DIM * H_DIM * PLANE) // 8388608

// ---------------------------------------------------------------------------
// Projection GEMM: out = X @ W^T + b, output fp16.
// X: [B=8192][1024] f32 row-major. W: [1024][1024] f32 row-major (row j = out col j).
// MODE 0: out[a][h][m][c]  (qp / kp layout)
// MODE 1: out[a][h][c][t]  (vp transposed layout)
// Tile: 128x128, BK=32, 4 waves (2x2), each wave 64x64 via 4x4 frags of 16x16x32.
// ---------------------------------------------------------------------------
template<int MODE>
__global__ __launch_bounds__(256)
void proj_kernel(const float* __restrict__ X, const float* __restrict__ W,
                 const float* __restrict__ bias, _Float16* __restrict__ out)
{
    __shared__ _Float16 lds_a[128][40];   // +8 pad: 80B row stride, 16B aligned
    __shared__ _Float16 lds_b[128][40];

    const int tid  = threadIdx.x;
    const int lane = tid & 63;
    const int wave = tid >> 6;
    const int wr = wave >> 1, wc = wave & 1;
    const int g = lane >> 4, r16 = lane & 15;
    const int R0 = blockIdx.x * 128;
    const int C0 = blockIdx.y * 128;

    float4v acc[4][4];
#pragma unroll
    for (int i = 0; i < 4; i++)
#pragma unroll
        for (int j = 0; j < 4; j++) acc[i][j] = {0.f, 0.f, 0.f, 0.f};

    for (int k0 = 0; k0 < E_DIM; k0 += 32) {
        __syncthreads();
        // stage A (X rows) and B (W rows = out cols), f32 -> fp16
#pragma unroll
        for (int i = 0; i < 4; i++) {
            int idx = tid + 256 * i;       // 0..1023
            int row = idx >> 3;            // 0..127
            int seg = idx & 7;             // 0..7, 4 f32 each
            float4v xa = *reinterpret_cast<const float4v*>(&X[(size_t)(R0 + row) * E_DIM + k0 + seg * 4]);
            float4v xb = *reinterpret_cast<const float4v*>(&W[(size_t)(C0 + row) * E_DIM + k0 + seg * 4]);
            half4 ha, hb;
#pragma unroll
            for (int q = 0; q < 4; q++) { ha[q] = (_Float16)xa[q]; hb[q] = (_Float16)xb[q]; }
            *reinterpret_cast<half4*>(&lds_a[row][seg * 4]) = ha;
            *reinterpret_cast<half4*>(&lds_b[row][seg * 4]) = hb;
        }
        __syncthreads();

        half8 af[4], bf[4];
#pragma unroll
        for (int mi = 0; mi < 4; mi++)
            af[mi] = *reinterpret_cast<const half8*>(&lds_a[wr * 64 + mi * 16 + r16][g * 8]);
#pragma unroll
        for (int ni = 0; ni < 4; ni++)
            bf[ni] = *reinterpret_cast<const half8*>(&lds_b[wc * 64 + ni * 16 + r16][g * 8]);
#pragma unroll
        for (int mi = 0; mi < 4; mi++)
#pragma unroll
            for (int ni = 0; ni < 4; ni++)
                acc[mi][ni] = __builtin_amdgcn_mfma_f32_16x16x32_f16(af[mi], bf[ni], acc[mi][ni], 0, 0, 0);
    }

    // epilogue: D layout col = lane&15, row = g*4 + reg
#pragma unroll
    for (int mi = 0; mi < 4; mi++) {
#pragma unroll
        for (int ni = 0; ni < 4; ni++) {
            const int jb = C0 + wc * 64 + ni * 16 + r16;  // output col 0..1023
            const int h  = jb >> 6;
            const int cc = jb & 63;
            const float bv = bias[jb];
            if (MODE == 0) {
#pragma unroll
                for (int reg = 0; reg < 4; reg++) {
                    int b = R0 + wr * 64 + mi * 16 + g * 4 + reg;   // row 0..8191
                    float val = acc[mi][ni][reg] + bv;
                    size_t o = (size_t)((b >> 11) * H_DIM + h) * PLANE + (size_t)(b & (M_DIM - 1)) * C_DIM + cc;
                    out[o] = (_Float16)val;
                }
            } else {
                int b0 = R0 + wr * 64 + mi * 16 + g * 4;
                half4 pk;
#pragma unroll
                for (int reg = 0; reg < 4; reg++) pk[reg] = (_Float16)(acc[mi][ni][reg] + bv);
                size_t o = (size_t)((b0 >> 11) * H_DIM + h) * PLANE + (size_t)cc * M_DIM + (b0 & (M_DIM - 1));
                *reinterpret_cast<half4*>(&out[o]) = pk;
            }
        }
    }
}

// ---------------------------------------------------------------------------
// Flash attention: one block per (a,h, 64-row q tile). 4 waves x 16 q-rows.
// qp,kp: fp16 [a][h][2048][64]; vt: fp16 [a][h][64][2048]; out f32 [a][2048][1024]
// Unscaled QK^T (faithful to reference), online softmax.
// ---------------------------------------------------------------------------
__global__ __launch_bounds__(256)
void flash_kernel(const _Float16* __restrict__ qp, const _Float16* __restrict__ kp,
                  const _Float16* __restrict__ vt, float* __restrict__ out)
{
    __shared__ _Float16 kt[64][72];       // K tile [t][c], +8 pad
    __shared__ _Float16 vtl[64][72];      // V^T tile [c][t], +8 pad
    __shared__ _Float16 plds[4][16][72];  // per-wave P transpose buffer

    const int tid  = threadIdx.x;
    const int lane = tid & 63;
    const int wave = tid >> 6;
    const int g = lane >> 4, r16 = lane & 15;

    const int bid = blockIdx.x;
    const int ah = bid >> 5;      // 0..63 : consecutive blocks share K/V (L2 locality)
    const int qt = bid & 31;
    const size_t plane = (size_t)ah * PLANE;
    const int q0 = qt * 64 + wave * 16;   // this wave's first q row

    // Q fragments hoisted to registers: A row = lane&15, k(c) = g*8 + ks*32
    half8 qf[2];
#pragma unroll
    for (int ks = 0; ks < 2; ks++)
        qf[ks] = *reinterpret_cast<const half8*>(&qp[plane + (size_t)(q0 + r16) * C_DIM + ks * 32 + g * 8]);

    float4v o_acc[4];
#pragma unroll
    for (int i = 0; i < 4; i++) o_acc[i] = {0.f, 0.f, 0.f, 0.f};
    float mrow[4], lrow[4];
#pragma unroll
    for (int r = 0; r < 4; r++) { mrow[r] = -INFINITY; lrow[r] = 0.f; }

    for (int t0 = 0; t0 < M_DIM; t0 += 64) {
        __syncthreads();   // guard K/V overwrite vs previous PV reads
#pragma unroll
        for (int i = 0; i < 2; i++) {
            int idx = tid + 256 * i;   // 0..511
            int row = idx >> 3;        // 0..63
            int seg = idx & 7;         // 8 f16 each
            *reinterpret_cast<half8*>(&kt[row][seg * 8]) =
                *reinterpret_cast<const half8*>(&kp[plane + (size_t)(t0 + row) * C_DIM + seg * 8]);
            *reinterpret_cast<half8*>(&vtl[row][seg * 8]) =
                *reinterpret_cast<const half8*>(&vt[plane + (size_t)row * M_DIM + t0 + seg * 8]);
        }
        __syncthreads();

        // S = Q K^T : s[ct] covers t = t0 + ct*16 + (lane&15), q row = g*4+reg
        float4v s[4];
#pragma unroll
        for (int ct = 0; ct < 4; ct++) {
            s[ct] = {0.f, 0.f, 0.f, 0.f};
#pragma unroll
            for (int ks = 0; ks < 2; ks++) {
                half8 kf = *reinterpret_cast<const half8*>(&kt[ct * 16 + r16][ks * 32 + g * 8]);
                s[ct] = __builtin_amdgcn_mfma_f32_16x16x32_f16(qf[ks], kf, s[ct], 0, 0, 0);
            }
        }

        // online softmax, wave-parallel (reduce across the 16-lane group)
#pragma unroll
        for (int r = 0; r < 4; r++) {
            float v = fmaxf(fmaxf(s[0][r], s[1][r]), fmaxf(s[2][r], s[3][r]));
            v = fmaxf(v, __shfl_xor(v, 1));
            v = fmaxf(v, __shfl_xor(v, 2));
            v = fmaxf(v, __shfl_xor(v, 4));
            v = fmaxf(v, __shfl_xor(v, 8));
            float mnew = fmaxf(mrow[r], v);
            float scale = __expf(mrow[r] - mnew);
            mrow[r] = mnew;
            float sum = 0.f;
#pragma unroll
            for (int ct = 0; ct < 4; ct++) {
                float p = __expf(s[ct][r] - mnew);
                s[ct][r] = p;
                sum += p;
            }
            sum += __shfl_xor(sum, 1);
            sum += __shfl_xor(sum, 2);
            sum += __shfl_xor(sum, 4);
            sum += __shfl_xor(sum, 8);
            lrow[r] = lrow[r] * scale + sum;
#pragma unroll
            for (int ct = 0; ct < 4; ct++) o_acc[ct][r] *= scale;
        }

        // transpose P through per-wave LDS: write D-layout, read A-layout
#pragma unroll
        for (int ct = 0; ct < 4; ct++)
#pragma unroll
            for (int r = 0; r < 4; r++)
                plds[wave][g * 4 + r][ct * 16 + r16] = (_Float16)s[ct][r];
        __syncthreads();

        // O += P V : A = P (row = lane&15 = q row, k = t), B = V (j = d, k = t)
#pragma unroll
        for (int ks = 0; ks < 2; ks++) {
            half8 pf = *reinterpret_cast<const half8*>(&plds[wave][r16][ks * 32 + g * 8]);
#pragma unroll
            for (int ct = 0; ct < 4; ct++) {
                half8 vf = *reinterpret_cast<const half8*>(&vtl[ct * 16 + r16][ks * 32 + g * 8]);
                o_acc[ct] = __builtin_amdgcn_mfma_f32_16x16x32_f16(pf, vf, o_acc[ct], 0, 0, 0);
            }
        }
    }

    // epilogue: out[a][m][h*64+d], d = ct*16 + lane&15, m row = q0 + g*4 + reg
    const int aa = ah >> 4;
    const int hh = ah & 15;
#pragma unroll
    for (int r = 0; r < 4; r++) {
        const int mm = q0 + g * 4 + r;
        const float inv = 1.0f / lrow[r];
#pragma unroll
        for (int ct = 0; ct < 4; ct++) {
            int d = ct * 16 + r16;
            out[(size_t)(aa * M_DIM + mm) * E_DIM + hh * C_DIM + d] = o_acc[ct][r] * inv;
        }
    }
}

extern "C" void kernel_launch(void* const* d_in, const int* in_sizes, int n_in,
                              void* d_out, int out_size, void* d_ws, size_t ws_size,
                              hipStream_t stream)
{
    const float* q  = (const float*)d_in[0];
    const float* k  = (const float*)d_in[1];
    const float* v  = (const float*)d_in[2];
    const float* Wq = (const float*)d_in[3];
    const float* bq = (const float*)d_in[4];
    const float* Wk = (const float*)d_in[5];
    const float* bk = (const float*)d_in[6];
    const float* Wv = (const float*)d_in[7];
    const float* bv = (const float*)d_in[8];
    float* out = (float*)d_out;

    _Float16* qp = (_Float16*)d_ws;
    _Float16* kp = qp + PROJ_ELEMS;
    _Float16* vt = kp + PROJ_ELEMS;

    dim3 pg(64, 8), pb(256);
    hipLaunchKernelGGL((proj_kernel<0>), pg, pb, 0, stream, q, Wq, bq, qp);
    hipLaunchKernelGGL((proj_kernel<0>), pg, pb, 0, stream, k, Wk, bk, kp);
    hipLaunchKernelGGL((proj_kernel<1>), pg, pb, 0, stream, v, Wv, bv, vt);
    hipLaunchKernelGGL(flash_kernel, dim3(A_DIM * H_DIM * (M_DIM / 64)), dim3(256), 0, stream, qp, kp, vt, out);
}

// Round 3
// 227.218 us; speedup vs baseline: 1.5337x; 1.5337x over previous
//
#include <hip/hip_runtime.h>
#include <hip/hip_bf16.h>
#include <hip/hip_fp16.h>

using half8  = __attribute__((ext_vector_type(8))) _Float16;
using half4  = __attribute__((ext_vector_type(4))) _Float16;
using float4v = __attribute__((ext_vector_type(4))) float;
using f32x16 = __attribute__((ext_vector_type(16))) float;
typedef unsigned int uint;

#define A_DIM 4
#define M_DIM 2048
#define E_DIM 1024
#define H_DIM 16
#define C_DIM 64
#define PLANE (M_DIM * C_DIM)              // 131072 elements per (a,h)
#define PROJ_ELEMS (A_DIM * H_DIM * PLANE) // 8388608

#define GLOAD_LDS16(g, l) __builtin_amdgcn_global_load_lds( \
    (const __attribute__((address_space(1))) void*)(g), \
    (__attribute__((address_space(3))) void*)(l), 16, 0, 0)

// f32 pair -> packed fp16 (RTZ) as uint bits
static __device__ __forceinline__ uint pk16(float a, float b) {
    auto r = __builtin_amdgcn_cvt_pkrtz(a, b);   // __fp16 x2
    return __builtin_bit_cast(uint, r);
}

// ---------------------------------------------------------------------------
// Projection GEMM (unchanged from R1): out = X @ W^T + b, fp16 out.
// MODE 0: out[a][h][m][c]  (qp / kp) ; MODE 1: out[a][h][c][t] (vp transposed)
// ---------------------------------------------------------------------------
template<int MODE>
__global__ __launch_bounds__(256)
void proj_kernel(const float* __restrict__ X, const float* __restrict__ W,
                 const float* __restrict__ bias, _Float16* __restrict__ out)
{
    __shared__ _Float16 lds_a[128][40];
    __shared__ _Float16 lds_b[128][40];

    const int tid  = threadIdx.x;
    const int lane = tid & 63;
    const int wave = tid >> 6;
    const int wr = wave >> 1, wc = wave & 1;
    const int g = lane >> 4, r16 = lane & 15;
    const int R0 = blockIdx.x * 128;
    const int C0 = blockIdx.y * 128;

    float4v acc[4][4];
#pragma unroll
    for (int i = 0; i < 4; i++)
#pragma unroll
        for (int j = 0; j < 4; j++) acc[i][j] = {0.f, 0.f, 0.f, 0.f};

    for (int k0 = 0; k0 < E_DIM; k0 += 32) {
        __syncthreads();
#pragma unroll
        for (int i = 0; i < 4; i++) {
            int idx = tid + 256 * i;
            int row = idx >> 3;
            int seg = idx & 7;
            float4v xa = *reinterpret_cast<const float4v*>(&X[(size_t)(R0 + row) * E_DIM + k0 + seg * 4]);
            float4v xb = *reinterpret_cast<const float4v*>(&W[(size_t)(C0 + row) * E_DIM + k0 + seg * 4]);
            half4 ha, hb;
#pragma unroll
            for (int q = 0; q < 4; q++) { ha[q] = (_Float16)xa[q]; hb[q] = (_Float16)xb[q]; }
            *reinterpret_cast<half4*>(&lds_a[row][seg * 4]) = ha;
            *reinterpret_cast<half4*>(&lds_b[row][seg * 4]) = hb;
        }
        __syncthreads();

        half8 af[4], bf[4];
#pragma unroll
        for (int mi = 0; mi < 4; mi++)
            af[mi] = *reinterpret_cast<const half8*>(&lds_a[wr * 64 + mi * 16 + r16][g * 8]);
#pragma unroll
        for (int ni = 0; ni < 4; ni++)
            bf[ni] = *reinterpret_cast<const half8*>(&lds_b[wc * 64 + ni * 16 + r16][g * 8]);
#pragma unroll
        for (int mi = 0; mi < 4; mi++)
#pragma unroll
            for (int ni = 0; ni < 4; ni++)
                acc[mi][ni] = __builtin_amdgcn_mfma_f32_16x16x32_f16(af[mi], bf[ni], acc[mi][ni], 0, 0, 0);
    }

#pragma unroll
    for (int mi = 0; mi < 4; mi++) {
#pragma unroll
        for (int ni = 0; ni < 4; ni++) {
            const int jb = C0 + wc * 64 + ni * 16 + r16;
            const int h  = jb >> 6;
            const int cc = jb & 63;
            const float bv = bias[jb];
            if (MODE == 0) {
#pragma unroll
                for (int reg = 0; reg < 4; reg++) {
                    int b = R0 + wr * 64 + mi * 16 + g * 4 + reg;
                    float val = acc[mi][ni][reg] + bv;
                    size_t o = (size_t)((b >> 11) * H_DIM + h) * PLANE + (size_t)(b & (M_DIM - 1)) * C_DIM + cc;
                    out[o] = (_Float16)val;
                }
            } else {
                int b0 = R0 + wr * 64 + mi * 16 + g * 4;
                half4 pkv;
#pragma unroll
                for (int reg = 0; reg < 4; reg++) pkv[reg] = (_Float16)(acc[mi][ni][reg] + bv);
                size_t o = (size_t)((b0 >> 11) * H_DIM + h) * PLANE + (size_t)cc * M_DIM + (b0 & (M_DIM - 1));
                *reinterpret_cast<half4*>(&out[o]) = pkv;
            }
        }
    }
}

// ---------------------------------------------------------------------------
// Flash attention, swapped-QK^T 32x32 structure.
// One block = 128 q-rows of one (a,h) plane; 4 waves x 32 q-rows.
// Per 64-t tile: K/V staged via global_load_lds (pre-swizzled src, XOR-swizzled
// reads), 1 barrier. S^T = mfma(K,Q) so each lane owns one q-row (q = lane&31).
// P^T rebuilt for PV B-operand with cvt_pkrtz + shfl_xor(32). O^T accumulated.
// ---------------------------------------------------------------------------
__global__ __launch_bounds__(256, 4)
void flash_kernel(const _Float16* __restrict__ qp, const _Float16* __restrict__ kp,
                  const _Float16* __restrict__ vt, float* __restrict__ out)
{
    __shared__ _Float16 smem[2][2][4096];   // [dbuf][K|V][64 rows x 64 cols]

    const int tid  = threadIdx.x;
    const int lane = tid & 63;
    const int wave = tid >> 6;
    const int l31  = lane & 31;
    const int hi   = lane >> 5;

    // XCD-chunked swizzle: 1024 wgs, 8 xcds -> each xcd owns 8 whole planes
    const int bid = blockIdx.x;
    const int wg  = ((bid & 7) << 7) | (bid >> 3);
    const int plane_i = wg >> 4;
    const int qt      = wg & 15;
    const size_t plane = (size_t)plane_i * PLANE;
    const int q0 = qt * 128 + wave * 32;

    // staging geometry: thread loads 2x16B per K buf and per V buf
    const int srow  = tid >> 3;                       // rows 0..31 (+32)
    const int lincb = (tid & 7) * 16;                 // linear col byte
    const int scb   = lincb ^ ((srow & 7) << 4);      // pre-swizzled source col

    // hoist Q fragments (B operand: col=q=lane&31, k = 8*hi + j per 16-c chunk)
    half8 qf[4];
#pragma unroll
    for (int ch = 0; ch < 4; ch++)
        qf[ch] = *reinterpret_cast<const half8*>(&qp[plane + (size_t)(q0 + l31) * C_DIM + ch * 16 + hi * 8]);

    f32x16 o0, o1;
#pragma unroll
    for (int i = 0; i < 16; i++) { o0[i] = 0.f; o1[i] = 0.f; }
    float m = -INFINITY, l = 0.f;

    auto stage = [&](int buf, int t0) {
#pragma unroll
        for (int i = 0; i < 2; i++) {
            int row = srow + 32 * i;
            const char* ksrc = (const char*)&kp[plane + (size_t)(t0 + row) * C_DIM] + scb;
            const char* vsrc = (const char*)&vt[plane + (size_t)row * M_DIM + t0] + scb;
            GLOAD_LDS16(ksrc, &smem[buf][0][tid * 8 + 2048 * i]);
            GLOAD_LDS16(vsrc, &smem[buf][1][tid * 8 + 2048 * i]);
        }
    };

    stage(0, 0);

    for (int it = 0; it < M_DIM / 64; ++it) {
        __syncthreads();                         // drains vmcnt, publishes stage
        if (it + 1 < M_DIM / 64) stage((it + 1) & 1, (it + 1) * 64);
        const int cur = it & 1;
        const char* kbase = (const char*)smem[cur][0];
        const char* vbase = (const char*)smem[cur][1];

#pragma unroll
        for (int st = 0; st < 2; ++st) {
            // ---- S^T = K * Q^T over c=64 (4 chunks of K=16) ----
            const int krow = st * 32 + l31;
            const int kswz = (krow & 7) << 4;
            f32x16 s;
#pragma unroll
            for (int i = 0; i < 16; i++) s[i] = 0.f;
#pragma unroll
            for (int ch = 0; ch < 4; ch++) {
                int cb = (ch * 32 + hi * 16) ^ kswz;
                half8 kf = *reinterpret_cast<const half8*>(kbase + krow * 128 + cb);
                s = __builtin_amdgcn_mfma_f32_32x32x16_f16(kf, qf[ch], s, 0, 0, 0);
            }

            // ---- online softmax: lane owns q-row (lane&31); halves via xor 32
            float pm = s[0];
#pragma unroll
            for (int r = 1; r < 16; r++) pm = fmaxf(pm, s[r]);
            pm = fmaxf(pm, __shfl_xor(pm, 32));
            if (pm > m + 8.f) {                  // defer-max (T13)
                float sc = __expf(m - pm);
                m = pm; l *= sc;
#pragma unroll
                for (int r = 0; r < 16; r++) { o0[r] *= sc; o1[r] *= sc; }
            }
            float ts = 0.f;
#pragma unroll
            for (int r = 0; r < 16; r++) { float p = __expf(s[r] - m); s[r] = p; ts += p; }
            ts += __shfl_xor(ts, 32);
            l += ts;

            // ---- pack P^T into PV B-operand fragments (lane<->lane+32) ----
            half8 pf[2];
#pragma unroll
            for (int c0 = 0; c0 < 2; c0++) {
                uint ua0 = pk16(s[8 * c0 + 0], s[8 * c0 + 1]);
                uint ua1 = pk16(s[8 * c0 + 2], s[8 * c0 + 3]);
                uint ub0 = pk16(s[8 * c0 + 4], s[8 * c0 + 5]);
                uint ub1 = pk16(s[8 * c0 + 6], s[8 * c0 + 7]);
                // send partner the half it needs, receive ours
                uint v0 = hi ? ua0 : ub0;
                uint v1 = hi ? ua1 : ub1;
                uint y0 = (uint)__shfl_xor((int)v0, 32);
                uint y1 = (uint)__shfl_xor((int)v1, 32);
                union { uint u[4]; half8 v; } pu;
                pu.u[0] = hi ? y0 : ua0;
                pu.u[1] = hi ? y1 : ua1;
                pu.u[2] = hi ? ub0 : y0;
                pu.u[3] = hi ? ub1 : y1;
                pf[c0] = pu.v;
            }

            // ---- O^T += V^T * P^T ----
#pragma unroll
            for (int db = 0; db < 2; db++) {
                const int vrow = db * 32 + l31;
                const int vswz = (vrow & 7) << 4;
#pragma unroll
                for (int c0 = 0; c0 < 2; c0++) {
                    int cb = (st * 64 + c0 * 32 + hi * 16) ^ vswz;
                    half8 vf = *reinterpret_cast<const half8*>(vbase + vrow * 128 + cb);
                    if (db == 0) o0 = __builtin_amdgcn_mfma_f32_32x32x16_f16(vf, pf[c0], o0, 0, 0, 0);
                    else         o1 = __builtin_amdgcn_mfma_f32_32x32x16_f16(vf, pf[c0], o1, 0, 0, 0);
                }
            }
        }
    }

    // ---- epilogue: O^T[d][q] -> out[a][m=q][h*64+d], float4 stores ----
    const int aa = plane_i >> 4;
    const int hh = plane_i & 15;
    const float inv = 1.f / l;
    float* obase = out + ((size_t)(aa * M_DIM + q0 + l31)) * E_DIM + hh * C_DIM;
#pragma unroll
    for (int db = 0; db < 2; db++) {
#pragma unroll
        for (int g4 = 0; g4 < 4; g4++) {
            float4v w;
#pragma unroll
            for (int j = 0; j < 4; j++) w[j] = (db ? o1[4 * g4 + j] : o0[4 * g4 + j]) * inv;
            int d0 = db * 32 + 8 * g4 + 4 * hi;
            *reinterpret_cast<float4v*>(obase + d0) = w;
        }
    }
}

extern "C" void kernel_launch(void* const* d_in, const int* in_sizes, int n_in,
                              void* d_out, int out_size, void* d_ws, size_t ws_size,
                              hipStream_t stream)
{
    const float* q  = (const float*)d_in[0];
    const float* k  = (const float*)d_in[1];
    const float* v  = (const float*)d_in[2];
    const float* Wq = (const float*)d_in[3];
    const float* bq = (const float*)d_in[4];
    const float* Wk = (const float*)d_in[5];
    const float* bk = (const float*)d_in[6];
    const float* Wv = (const float*)d_in[7];
    const float* bv = (const float*)d_in[8];
    float* out = (float*)d_out;

    _Float16* qp = (_Float16*)d_ws;
    _Float16* kp = qp + PROJ_ELEMS;
    _Float16* vt = kp + PROJ_ELEMS;

    dim3 pg(64, 8), pb(256);
    hipLaunchKernelGGL((proj_kernel<0>), pg, pb, 0, stream, q, Wq, bq, qp);
    hipLaunchKernelGGL((proj_kernel<0>), pg, pb, 0, stream, k, Wk, bk, kp);
    hipLaunchKernelGGL((proj_kernel<1>), pg, pb, 0, stream, v, Wv, bv, vt);
    hipLaunchKernelGGL(flash_kernel, dim3(A_DIM * H_DIM * (M_DIM / 128)), dim3(256), 0, stream, qp, kp, vt, out);
}

// Round 5
// 226.202 us; speedup vs baseline: 1.5406x; 1.0045x over previous
//
#include <hip/hip_runtime.h>
#include <hip/hip_bf16.h>
#include <hip/hip_fp16.h>

using half8  = __attribute__((ext_vector_type(8))) _Float16;
using half4  = __attribute__((ext_vector_type(4))) _Float16;
using float4v = __attribute__((ext_vector_type(4))) float;
using f32x16 = __attribute__((ext_vector_type(16))) float;
typedef unsigned int uint;

#define A_DIM 4
#define M_DIM 2048
#define E_DIM 1024
#define H_DIM 16
#define C_DIM 64
#define PLANE (M_DIM * C_DIM)              // 131072 elements per (a,h)
#define PROJ_ELEMS (A_DIM * H_DIM * PLANE) // 8388608
#define LOG2E 1.44269504088896f

#define GLOAD_LDS16(g, l) __builtin_amdgcn_global_load_lds( \
    (const __attribute__((address_space(1))) void*)(g), \
    (__attribute__((address_space(3))) void*)(l), 16, 0, 0)

#if __has_builtin(__builtin_amdgcn_exp2f)
#define EXP2F(x) __builtin_amdgcn_exp2f(x)
#else
#define EXP2F(x) exp2f(x)
#endif

// f32 pair -> packed fp16 (RTZ) as uint bits
static __device__ __forceinline__ uint pk16(float a, float b) {
    auto r = __builtin_amdgcn_cvt_pkrtz(a, b);   // __fp16 x2
    return __builtin_bit_cast(uint, r);
}

// ---------------------------------------------------------------------------
// Projection GEMM (unchanged): out = X @ W^T + b, fp16 out.
// MODE 0: out[a][h][m][c]  (qp / kp) ; MODE 1: out[a][h][c][t] (vp transposed)
// ---------------------------------------------------------------------------
template<int MODE>
__global__ __launch_bounds__(256)
void proj_kernel(const float* __restrict__ X, const float* __restrict__ W,
                 const float* __restrict__ bias, _Float16* __restrict__ out)
{
    __shared__ _Float16 lds_a[128][40];
    __shared__ _Float16 lds_b[128][40];

    const int tid  = threadIdx.x;
    const int lane = tid & 63;
    const int wave = tid >> 6;
    const int wr = wave >> 1, wc = wave & 1;
    const int g = lane >> 4, r16 = lane & 15;
    const int R0 = blockIdx.x * 128;
    const int C0 = blockIdx.y * 128;

    float4v acc[4][4];
#pragma unroll
    for (int i = 0; i < 4; i++)
#pragma unroll
        for (int j = 0; j < 4; j++) acc[i][j] = {0.f, 0.f, 0.f, 0.f};

    for (int k0 = 0; k0 < E_DIM; k0 += 32) {
        __syncthreads();
#pragma unroll
        for (int i = 0; i < 4; i++) {
            int idx = tid + 256 * i;
            int row = idx >> 3;
            int seg = idx & 7;
            float4v xa = *reinterpret_cast<const float4v*>(&X[(size_t)(R0 + row) * E_DIM + k0 + seg * 4]);
            float4v xb = *reinterpret_cast<const float4v*>(&W[(size_t)(C0 + row) * E_DIM + k0 + seg * 4]);
            half4 ha, hb;
#pragma unroll
            for (int q = 0; q < 4; q++) { ha[q] = (_Float16)xa[q]; hb[q] = (_Float16)xb[q]; }
            *reinterpret_cast<half4*>(&lds_a[row][seg * 4]) = ha;
            *reinterpret_cast<half4*>(&lds_b[row][seg * 4]) = hb;
        }
        __syncthreads();

        half8 af[4], bf[4];
#pragma unroll
        for (int mi = 0; mi < 4; mi++)
            af[mi] = *reinterpret_cast<const half8*>(&lds_a[wr * 64 + mi * 16 + r16][g * 8]);
#pragma unroll
        for (int ni = 0; ni < 4; ni++)
            bf[ni] = *reinterpret_cast<const half8*>(&lds_b[wc * 64 + ni * 16 + r16][g * 8]);
#pragma unroll
        for (int mi = 0; mi < 4; mi++)
#pragma unroll
            for (int ni = 0; ni < 4; ni++)
                acc[mi][ni] = __builtin_amdgcn_mfma_f32_16x16x32_f16(af[mi], bf[ni], acc[mi][ni], 0, 0, 0);
    }

#pragma unroll
    for (int mi = 0; mi < 4; mi++) {
#pragma unroll
        for (int ni = 0; ni < 4; ni++) {
            const int jb = C0 + wc * 64 + ni * 16 + r16;
            const int h  = jb >> 6;
            const int cc = jb & 63;
            const float bv = bias[jb];
            if (MODE == 0) {
#pragma unroll
                for (int reg = 0; reg < 4; reg++) {
                    int b = R0 + wr * 64 + mi * 16 + g * 4 + reg;
                    float val = acc[mi][ni][reg] + bv;
                    size_t o = (size_t)((b >> 11) * H_DIM + h) * PLANE + (size_t)(b & (M_DIM - 1)) * C_DIM + cc;
                    out[o] = (_Float16)val;
                }
            } else {
                int b0 = R0 + wr * 64 + mi * 16 + g * 4;
                half4 pkv;
#pragma unroll
                for (int reg = 0; reg < 4; reg++) pkv[reg] = (_Float16)(acc[mi][ni][reg] + bv);
                size_t o = (size_t)((b0 >> 11) * H_DIM + h) * PLANE + (size_t)cc * M_DIM + (b0 & (M_DIM - 1));
                *reinterpret_cast<half4*>(&out[o]) = pkv;
            }
        }
    }
}

// ---------------------------------------------------------------------------
// Flash attention, swapped-QK^T 32x32 structure. Lane exchange via verified
// shfl_xor pack (R3); max3 tree, exp2+fma, uniform defer-max, setprio on MFMA.
// ---------------------------------------------------------------------------
__global__ __launch_bounds__(256, 4)
void flash_kernel(const _Float16* __restrict__ qp, const _Float16* __restrict__ kp,
                  const _Float16* __restrict__ vt, float* __restrict__ out)
{
    __shared__ _Float16 smem[2][2][4096];   // [dbuf][K|V][64 rows x 64 cols]

    const int tid  = threadIdx.x;
    const int lane = tid & 63;
    const int wave = tid >> 6;
    const int l31  = lane & 31;
    const int hi   = lane >> 5;

    // XCD-chunked swizzle: 1024 wgs, 8 xcds -> each xcd owns 8 whole planes
    const int bid = blockIdx.x;
    const int wg  = ((bid & 7) << 7) | (bid >> 3);
    const int plane_i = wg >> 4;
    const int qt      = wg & 15;
    const size_t plane = (size_t)plane_i * PLANE;
    const int q0 = qt * 128 + wave * 32;

    // staging geometry: thread loads 2x16B per K buf and per V buf
    const int srow  = tid >> 3;                       // rows 0..31 (+32)
    const int lincb = (tid & 7) * 16;                 // linear col byte
    const int scb   = lincb ^ ((srow & 7) << 4);      // pre-swizzled source col

    // hoist Q fragments (B operand: col=q=lane&31, k = 8*hi + j per 16-c chunk)
    half8 qf[4];
#pragma unroll
    for (int ch = 0; ch < 4; ch++)
        qf[ch] = *reinterpret_cast<const half8*>(&qp[plane + (size_t)(q0 + l31) * C_DIM + ch * 16 + hi * 8]);

    f32x16 o0, o1;
#pragma unroll
    for (int i = 0; i < 16; i++) { o0[i] = 0.f; o1[i] = 0.f; }
    float m = -INFINITY, l = 0.f;   // l = own-half partial; cross-summed at end

    auto stage = [&](int buf, int t0) {
#pragma unroll
        for (int i = 0; i < 2; i++) {
            int row = srow + 32 * i;
            const char* ksrc = (const char*)&kp[plane + (size_t)(t0 + row) * C_DIM] + scb;
            const char* vsrc = (const char*)&vt[plane + (size_t)row * M_DIM + t0] + scb;
            GLOAD_LDS16(ksrc, &smem[buf][0][tid * 8 + 2048 * i]);
            GLOAD_LDS16(vsrc, &smem[buf][1][tid * 8 + 2048 * i]);
        }
    };

    stage(0, 0);

    for (int it = 0; it < M_DIM / 64; ++it) {
        __syncthreads();                         // drains vmcnt, publishes stage
        if (it + 1 < M_DIM / 64) stage((it + 1) & 1, (it + 1) * 64);
        const int cur = it & 1;
        const char* kbase = (const char*)smem[cur][0];
        const char* vbase = (const char*)smem[cur][1];

#pragma unroll
        for (int st = 0; st < 2; ++st) {
            // ---- S^T = K * Q^T over c=64 (4 chunks of K=16) ----
            const int krow = st * 32 + l31;
            const int kswz = (krow & 7) << 4;
            f32x16 s;
#pragma unroll
            for (int i = 0; i < 16; i++) s[i] = 0.f;
            __builtin_amdgcn_s_setprio(1);
#pragma unroll
            for (int ch = 0; ch < 4; ch++) {
                int cb = (ch * 32 + hi * 16) ^ kswz;
                half8 kf = *reinterpret_cast<const half8*>(kbase + krow * 128 + cb);
                s = __builtin_amdgcn_mfma_f32_32x32x16_f16(kf, qf[ch], s, 0, 0, 0);
            }
            __builtin_amdgcn_s_setprio(0);

            // ---- online softmax: lane owns q-row (lane&31) ----
            float a0 = fmaxf(fmaxf(s[0],  s[1]),  s[2]);
            float a1 = fmaxf(fmaxf(s[3],  s[4]),  s[5]);
            float a2 = fmaxf(fmaxf(s[6],  s[7]),  s[8]);
            float a3 = fmaxf(fmaxf(s[9],  s[10]), s[11]);
            float a4 = fmaxf(fmaxf(s[12], s[13]), s[14]);
            float pm = fmaxf(fmaxf(fmaxf(a0, a1), a2),
                             fmaxf(fmaxf(a3, a4), s[15]));
            pm = fmaxf(pm, __shfl_xor(pm, 32));   // pair-uniform max (verified)
            if (!__all(pm <= m + 8.f)) {          // defer-max (T13), wave-uniform
                float mnew = fmaxf(m, pm);
                float sc = EXP2F((m - mnew) * LOG2E);
                m = mnew; l *= sc;
                o0 *= sc; o1 *= sc;               // vector op -> packed mults
            }
            const float mK = m * LOG2E;
            float p[16];
#pragma unroll
            for (int r = 0; r < 16; r++) p[r] = EXP2F(fmaf(s[r], LOG2E, -mK));
            float t0a = (p[0] + p[1]) + (p[2] + p[3]);
            float t1a = (p[4] + p[5]) + (p[6] + p[7]);
            float t2a = (p[8] + p[9]) + (p[10] + p[11]);
            float t3a = (p[12] + p[13]) + (p[14] + p[15]);
            l += (t0a + t1a) + (t2a + t3a);       // own half only; swap at end

            // ---- pack P^T into PV B-operand fragments (R3-verified) ----
            half8 pf[2];
#pragma unroll
            for (int c0 = 0; c0 < 2; c0++) {
                uint ua0 = pk16(p[8 * c0 + 0], p[8 * c0 + 1]);
                uint ua1 = pk16(p[8 * c0 + 2], p[8 * c0 + 3]);
                uint ub0 = pk16(p[8 * c0 + 4], p[8 * c0 + 5]);
                uint ub1 = pk16(p[8 * c0 + 6], p[8 * c0 + 7]);
                uint v0 = hi ? ua0 : ub0;
                uint v1 = hi ? ua1 : ub1;
                uint y0 = (uint)__shfl_xor((int)v0, 32);
                uint y1 = (uint)__shfl_xor((int)v1, 32);
                union { uint u[4]; half8 v; } pu;
                pu.u[0] = hi ? y0 : ua0;
                pu.u[1] = hi ? y1 : ua1;
                pu.u[2] = hi ? ub0 : y0;
                pu.u[3] = hi ? ub1 : y1;
                pf[c0] = pu.v;
            }

            // ---- O^T += V^T * P^T ----
            __builtin_amdgcn_s_setprio(1);
#pragma unroll
            for (int db = 0; db < 2; db++) {
                const int vrow = db * 32 + l31;
                const int vswz = (vrow & 7) << 4;
#pragma unroll
                for (int c0 = 0; c0 < 2; c0++) {
                    int cb = (st * 64 + c0 * 32 + hi * 16) ^ vswz;
                    half8 vf = *reinterpret_cast<const half8*>(vbase + vrow * 128 + cb);
                    if (db == 0) o0 = __builtin_amdgcn_mfma_f32_32x32x16_f16(vf, pf[c0], o0, 0, 0, 0);
                    else         o1 = __builtin_amdgcn_mfma_f32_32x32x16_f16(vf, pf[c0], o1, 0, 0, 0);
                }
            }
            __builtin_amdgcn_s_setprio(0);
        }
    }

    // ---- epilogue: O^T[d][q] -> out[a][m=q][h*64+d], float4 stores ----
    const int aa = plane_i >> 4;
    const int hh = plane_i & 15;
    const float lt = l + __shfl_xor(l, 32);       // cross-half total (verified)
    const float inv = 1.f / lt;
    float* obase = out + ((size_t)(aa * M_DIM + q0 + l31)) * E_DIM + hh * C_DIM;
#pragma unroll
    for (int db = 0; db < 2; db++) {
#pragma unroll
        for (int g4 = 0; g4 < 4; g4++) {
            float4v w;
#pragma unroll
            for (int j = 0; j < 4; j++) w[j] = (db ? o1[4 * g4 + j] : o0[4 * g4 + j]) * inv;
            int d0 = db * 32 + 8 * g4 + 4 * hi;
            *reinterpret_cast<float4v*>(obase + d0) = w;
        }
    }
}

extern "C" void kernel_launch(void* const* d_in, const int* in_sizes, int n_in,
                              void* d_out, int out_size, void* d_ws, size_t ws_size,
                              hipStream_t stream)
{
    const float* q  = (const float*)d_in[0];
    const float* k  = (const float*)d_in[1];
    const float* v  = (const float*)d_in[2];
    const float* Wq = (const float*)d_in[3];
    const float* bq = (const float*)d_in[4];
    const float* Wk = (const float*)d_in[5];
    const float* bk = (const float*)d_in[6];
    const float* Wv = (const float*)d_in[7];
    const float* bv = (const float*)d_in[8];
    float* out = (float*)d_out;

    _Float16* qp = (_Float16*)d_ws;
    _Float16* kp = qp + PROJ_ELEMS;
    _Float16* vt = kp + PROJ_ELEMS;

    dim3 pg(64, 8), pb(256);
    hipLaunchKernelGGL((proj_kernel<0>), pg, pb, 0, stream, q, Wq, bq, qp);
    hipLaunchKernelGGL((proj_kernel<0>), pg, pb, 0, stream, k, Wk, bk, kp);
    hipLaunchKernelGGL((proj_kernel<1>), pg, pb, 0, stream, v, Wv, bv, vt);
    hipLaunchKernelGGL(flash_kernel, dim3(A_DIM * H_DIM * (M_DIM / 128)), dim3(256), 0, stream, qp, kp, vt, out);
}

// Round 6
// 206.772 us; speedup vs baseline: 1.6854x; 1.0940x over previous
//
#include <hip/hip_runtime.h>
#include <hip/hip_bf16.h>
#include <hip/hip_fp16.h>

using half8  = __attribute__((ext_vector_type(8))) _Float16;
using float4v = __attribute__((ext_vector_type(4))) float;
using f32x16 = __attribute__((ext_vector_type(16))) float;
typedef unsigned int uint;

#define A_DIM 4
#define M_DIM 2048
#define E_DIM 1024
#define H_DIM 16
#define C_DIM 64
#define PLANE (M_DIM * C_DIM)              // 131072 elements per (a,h)
#define PROJ_ELEMS (A_DIM * H_DIM * PLANE) // 8388608
#define LOG2E 1.44269504088896f

#define GLOAD_LDS16(g, l) __builtin_amdgcn_global_load_lds( \
    (const __attribute__((address_space(1))) void*)(g), \
    (__attribute__((address_space(3))) void*)(l), 16, 0, 0)

#if __has_builtin(__builtin_amdgcn_exp2f)
#define EXP2F(x) __builtin_amdgcn_exp2f(x)
#else
#define EXP2F(x) exp2f(x)
#endif

// f32 pair -> packed fp16 (RTZ) as uint bits
static __device__ __forceinline__ uint pk16(float a, float b) {
    auto r = __builtin_amdgcn_cvt_pkrtz(a, b);   // __fp16 x2
    return __builtin_bit_cast(uint, r);
}

// read 8 logical-contiguous f32 from a swizzled LDS tile row, convert to half8
// tile layout: [128 rows][64 f32], row stride 256B, 16B blocks XOR'd by (row&7)<<4
static __device__ __forceinline__ half8 ldsfrag_cvt(const float* base, int row, int colbyte) {
    const char* b = (const char*)base;
    int off = row * 256 + (colbyte ^ ((row & 7) << 4));
    float4v x0 = *reinterpret_cast<const float4v*>(b + off);
    float4v x1 = *reinterpret_cast<const float4v*>(b + (off ^ 16));
    union { uint u[4]; half8 v; } r;
    r.u[0] = pk16(x0[0], x0[1]);
    r.u[1] = pk16(x0[2], x0[3]);
    r.u[2] = pk16(x1[0], x1[1]);
    r.u[3] = pk16(x1[2], x1[3]);
    return r.v;
}

// ---------------------------------------------------------------------------
// Projection GEMM: out = X @ W^T + b, fp16 out. m97 structure:
// f32 tiles staged via global_load_lds (pre-swizzled source, rule 21),
// f32->f16 conversion at fragment read (cvt_pkrtz), BK=64, 2-barrier loop.
// MODE 0: out[a][h][m][c]  (qp / kp) ; MODE 1: out[a][h][c][t] (vp transposed)
// ---------------------------------------------------------------------------
template<int MODE>
__global__ __launch_bounds__(256, 2)
void proj_kernel(const float* __restrict__ X, const float* __restrict__ W,
                 const float* __restrict__ bias, _Float16* __restrict__ out)
{
    __shared__ float ldsA[128 * 64];   // 32 KB
    __shared__ float ldsB[128 * 64];   // 32 KB

    const int tid  = threadIdx.x;
    const int lane = tid & 63;
    const int wave = tid >> 6;
    const int wr = wave >> 1, wc = wave & 1;
    const int g = lane >> 4, r16 = lane & 15;
    const int R0 = blockIdx.x * 128;
    const int C0 = blockIdx.y * 128;

    // per-thread staging geometry (8 segs of 16B per matrix per K-step)
    // seg = i*256 + tid ; row = seg>>4 ; swizzled col byte within 256B row
    float4v acc[4][4];
#pragma unroll
    for (int i = 0; i < 4; i++)
#pragma unroll
        for (int j = 0; j < 4; j++) acc[i][j] = {0.f, 0.f, 0.f, 0.f};

    for (int k0 = 0; k0 < E_DIM; k0 += 64) {
        __syncthreads();                       // previous compute done
#pragma unroll
        for (int i = 0; i < 8; i++) {
            int seg  = i * 256 + tid;
            int row  = seg >> 4;
            int swzo = ((seg & 15) * 16) ^ ((row & 7) << 4);
            const char* asrc = (const char*)&X[(size_t)(R0 + row) * E_DIM + k0] + swzo;
            const char* bsrc = (const char*)&W[(size_t)(C0 + row) * E_DIM + k0] + swzo;
            GLOAD_LDS16(asrc, &ldsA[seg * 4]);
            GLOAD_LDS16(bsrc, &ldsB[seg * 4]);
        }
        __syncthreads();                       // drains vmcnt, publishes tiles

#pragma unroll
        for (int kc = 0; kc < 2; kc++) {
            const int cb = kc * 128 + g * 32;
            half8 af[4], bf[4];
#pragma unroll
            for (int mi = 0; mi < 4; mi++)
                af[mi] = ldsfrag_cvt(ldsA, wr * 64 + mi * 16 + r16, cb);
#pragma unroll
            for (int ni = 0; ni < 4; ni++)
                bf[ni] = ldsfrag_cvt(ldsB, wc * 64 + ni * 16 + r16, cb);
#pragma unroll
            for (int mi = 0; mi < 4; mi++)
#pragma unroll
                for (int ni = 0; ni < 4; ni++)
                    acc[mi][ni] = __builtin_amdgcn_mfma_f32_16x16x32_f16(af[mi], bf[ni], acc[mi][ni], 0, 0, 0);
        }
    }

    // epilogue: D layout col = lane&15, row = g*4 + reg
#pragma unroll
    for (int mi = 0; mi < 4; mi++) {
#pragma unroll
        for (int ni = 0; ni < 4; ni++) {
            const int jb = C0 + wc * 64 + ni * 16 + r16;
            const int h  = jb >> 6;
            const int cc = jb & 63;
            const float bv = bias[jb];
            if (MODE == 0) {
#pragma unroll
                for (int reg = 0; reg < 4; reg++) {
                    int b = R0 + wr * 64 + mi * 16 + g * 4 + reg;
                    float val = acc[mi][ni][reg] + bv;
                    size_t o = (size_t)((b >> 11) * H_DIM + h) * PLANE + (size_t)(b & (M_DIM - 1)) * C_DIM + cc;
                    out[o] = (_Float16)val;
                }
            } else {
                int b0 = R0 + wr * 64 + mi * 16 + g * 4;
                union { uint u[2]; _Float16 h[4]; } pkv;
                pkv.u[0] = pk16(acc[mi][ni][0] + bv, acc[mi][ni][1] + bv);
                pkv.u[1] = pk16(acc[mi][ni][2] + bv, acc[mi][ni][3] + bv);
                size_t o = (size_t)((b0 >> 11) * H_DIM + h) * PLANE + (size_t)cc * M_DIM + (b0 & (M_DIM - 1));
                *reinterpret_cast<uint*>(&out[o]) = pkv.u[0];
                *reinterpret_cast<uint*>(&out[o] + 2) = pkv.u[1];
            }
        }
    }
}

// ---------------------------------------------------------------------------
// Flash attention (FROZEN from R5): swapped-QK^T 32x32, shfl_xor pack,
// max3 tree, exp2+fma, uniform defer-max, setprio on MFMA. 104.6 us measured.
// ---------------------------------------------------------------------------
__global__ __launch_bounds__(256, 4)
void flash_kernel(const _Float16* __restrict__ qp, const _Float16* __restrict__ kp,
                  const _Float16* __restrict__ vt, float* __restrict__ out)
{
    __shared__ _Float16 smem[2][2][4096];   // [dbuf][K|V][64 rows x 64 cols]

    const int tid  = threadIdx.x;
    const int lane = tid & 63;
    const int wave = tid >> 6;
    const int l31  = lane & 31;
    const int hi   = lane >> 5;

    const int bid = blockIdx.x;
    const int wg  = ((bid & 7) << 7) | (bid >> 3);
    const int plane_i = wg >> 4;
    const int qt      = wg & 15;
    const size_t plane = (size_t)plane_i * PLANE;
    const int q0 = qt * 128 + wave * 32;

    const int srow  = tid >> 3;
    const int lincb = (tid & 7) * 16;
    const int scb   = lincb ^ ((srow & 7) << 4);

    half8 qf[4];
#pragma unroll
    for (int ch = 0; ch < 4; ch++)
        qf[ch] = *reinterpret_cast<const half8*>(&qp[plane + (size_t)(q0 + l31) * C_DIM + ch * 16 + hi * 8]);

    f32x16 o0, o1;
#pragma unroll
    for (int i = 0; i < 16; i++) { o0[i] = 0.f; o1[i] = 0.f; }
    float m = -INFINITY, l = 0.f;

    auto stage = [&](int buf, int t0) {
#pragma unroll
        for (int i = 0; i < 2; i++) {
            int row = srow + 32 * i;
            const char* ksrc = (const char*)&kp[plane + (size_t)(t0 + row) * C_DIM] + scb;
            const char* vsrc = (const char*)&vt[plane + (size_t)row * M_DIM + t0] + scb;
            GLOAD_LDS16(ksrc, &smem[buf][0][tid * 8 + 2048 * i]);
            GLOAD_LDS16(vsrc, &smem[buf][1][tid * 8 + 2048 * i]);
        }
    };

    stage(0, 0);

    for (int it = 0; it < M_DIM / 64; ++it) {
        __syncthreads();
        if (it + 1 < M_DIM / 64) stage((it + 1) & 1, (it + 1) * 64);
        const int cur = it & 1;
        const char* kbase = (const char*)smem[cur][0];
        const char* vbase = (const char*)smem[cur][1];

#pragma unroll
        for (int st = 0; st < 2; ++st) {
            const int krow = st * 32 + l31;
            const int kswz = (krow & 7) << 4;
            f32x16 s;
#pragma unroll
            for (int i = 0; i < 16; i++) s[i] = 0.f;
            __builtin_amdgcn_s_setprio(1);
#pragma unroll
            for (int ch = 0; ch < 4; ch++) {
                int cb = (ch * 32 + hi * 16) ^ kswz;
                half8 kf = *reinterpret_cast<const half8*>(kbase + krow * 128 + cb);
                s = __builtin_amdgcn_mfma_f32_32x32x16_f16(kf, qf[ch], s, 0, 0, 0);
            }
            __builtin_amdgcn_s_setprio(0);

            float a0 = fmaxf(fmaxf(s[0],  s[1]),  s[2]);
            float a1 = fmaxf(fmaxf(s[3],  s[4]),  s[5]);
            float a2 = fmaxf(fmaxf(s[6],  s[7]),  s[8]);
            float a3 = fmaxf(fmaxf(s[9],  s[10]), s[11]);
            float a4 = fmaxf(fmaxf(s[12], s[13]), s[14]);
            float pm = fmaxf(fmaxf(fmaxf(a0, a1), a2),
                             fmaxf(fmaxf(a3, a4), s[15]));
            pm = fmaxf(pm, __shfl_xor(pm, 32));
            if (!__all(pm <= m + 8.f)) {
                float mnew = fmaxf(m, pm);
                float sc = EXP2F((m - mnew) * LOG2E);
                m = mnew; l *= sc;
                o0 *= sc; o1 *= sc;
            }
            const float mK = m * LOG2E;
            float p[16];
#pragma unroll
            for (int r = 0; r < 16; r++) p[r] = EXP2F(fmaf(s[r], LOG2E, -mK));
            float t0a = (p[0] + p[1]) + (p[2] + p[3]);
            float t1a = (p[4] + p[5]) + (p[6] + p[7]);
            float t2a = (p[8] + p[9]) + (p[10] + p[11]);
            float t3a = (p[12] + p[13]) + (p[14] + p[15]);
            l += (t0a + t1a) + (t2a + t3a);

            half8 pf[2];
#pragma unroll
            for (int c0 = 0; c0 < 2; c0++) {
                uint ua0 = pk16(p[8 * c0 + 0], p[8 * c0 + 1]);
                uint ua1 = pk16(p[8 * c0 + 2], p[8 * c0 + 3]);
                uint ub0 = pk16(p[8 * c0 + 4], p[8 * c0 + 5]);
                uint ub1 = pk16(p[8 * c0 + 6], p[8 * c0 + 7]);
                uint v0 = hi ? ua0 : ub0;
                uint v1 = hi ? ua1 : ub1;
                uint y0 = (uint)__shfl_xor((int)v0, 32);
                uint y1 = (uint)__shfl_xor((int)v1, 32);
                union { uint u[4]; half8 v; } pu;
                pu.u[0] = hi ? y0 : ua0;
                pu.u[1] = hi ? y1 : ua1;
                pu.u[2] = hi ? ub0 : y0;
                pu.u[3] = hi ? ub1 : y1;
                pf[c0] = pu.v;
            }

            __builtin_amdgcn_s_setprio(1);
#pragma unroll
            for (int db = 0; db < 2; db++) {
                const int vrow = db * 32 + l31;
                const int vswz = (vrow & 7) << 4;
#pragma unroll
                for (int c0 = 0; c0 < 2; c0++) {
                    int cb = (st * 64 + c0 * 32 + hi * 16) ^ vswz;
                    half8 vf = *reinterpret_cast<const half8*>(vbase + vrow * 128 + cb);
                    if (db == 0) o0 = __builtin_amdgcn_mfma_f32_32x32x16_f16(vf, pf[c0], o0, 0, 0, 0);
                    else         o1 = __builtin_amdgcn_mfma_f32_32x32x16_f16(vf, pf[c0], o1, 0, 0, 0);
                }
            }
            __builtin_amdgcn_s_setprio(0);
        }
    }

    const int aa = plane_i >> 4;
    const int hh = plane_i & 15;
    const float lt = l + __shfl_xor(l, 32);
    const float inv = 1.f / lt;
    float* obase = out + ((size_t)(aa * M_DIM + q0 + l31)) * E_DIM + hh * C_DIM;
#pragma unroll
    for (int db = 0; db < 2; db++) {
#pragma unroll
        for (int g4 = 0; g4 < 4; g4++) {
            float4v w;
#pragma unroll
            for (int j = 0; j < 4; j++) w[j] = (db ? o1[4 * g4 + j] : o0[4 * g4 + j]) * inv;
            int d0 = db * 32 + 8 * g4 + 4 * hi;
            *reinterpret_cast<float4v*>(obase + d0) = w;
        }
    }
}

extern "C" void kernel_launch(void* const* d_in, const int* in_sizes, int n_in,
                              void* d_out, int out_size, void* d_ws, size_t ws_size,
                              hipStream_t stream)
{
    const float* q  = (const float*)d_in[0];
    const float* k  = (const float*)d_in[1];
    const float* v  = (const float*)d_in[2];
    const float* Wq = (const float*)d_in[3];
    const float* bq = (const float*)d_in[4];
    const float* Wk = (const float*)d_in[5];
    const float* bk = (const float*)d_in[6];
    const float* Wv = (const float*)d_in[7];
    const float* bv = (const float*)d_in[8];
    float* out = (float*)d_out;

    _Float16* qp = (_Float16*)d_ws;
    _Float16* kp = qp + PROJ_ELEMS;
    _Float16* vt = kp + PROJ_ELEMS;

    dim3 pg(64, 8), pb(256);
    hipLaunchKernelGGL((proj_kernel<0>), pg, pb, 0, stream, q, Wq, bq, qp);
    hipLaunchKernelGGL((proj_kernel<0>), pg, pb, 0, stream, k, Wk, bk, kp);
    hipLaunchKernelGGL((proj_kernel<1>), pg, pb, 0, stream, v, Wv, bv, vt);
    hipLaunchKernelGGL(flash_kernel, dim3(A_DIM * H_DIM * (M_DIM / 128)), dim3(256), 0, stream, qp, kp, vt, out);
}